// Round 1
// baseline (86.031 us; speedup 1.0000x reference)
//
#include <hip/hip_runtime.h>
#include <hip/hip_bf16.h>

typedef short bf16x8 __attribute__((ext_vector_type(8)));
typedef short bf16x4 __attribute__((ext_vector_type(4)));
typedef float f32x4  __attribute__((ext_vector_type(4)));

#define NI 256
#define NJ 256
#define NC 128
#define NH 4
#define ND 32

// ---- LDS layout (bytes) ----
#define XN_OFF 0
#define XN_STR 272              // 136 bf16 per row (pad 128->136)
#define Q_OFF  69632            // [256][40] bf16, stride 80B
#define K_OFF  90112
#define QK_STR 80
#define VT_OFF 110592           // [32][264] bf16, stride 528B
#define VT_STR 528
#define PB_OFF 127488           // 8 waves x [16][40] bf16
#define PB_STR 80
#define TB_OFF 137728           // [4][256] f32
#define MB_OFF 141824           // [256] f32
#define SMEM_BYTES 142848

__device__ __forceinline__ short f2bf(float f) {
    return __builtin_bit_cast(short, __float2bfloat16(f));
}
__device__ __forceinline__ float bf2f(short s) {
    unsigned u = ((unsigned)(unsigned short)s) << 16;
    return __builtin_bit_cast(float, u);
}

__global__ __launch_bounds__(512, 2)
void fta_fused(const float* __restrict__ x, const float* __restrict__ mask,
               const float* __restrict__ ln_g, const float* __restrict__ ln_b,
               const float* __restrict__ wq, const float* __restrict__ wk,
               const float* __restrict__ wv, const float* __restrict__ wb,
               const float* __restrict__ wo, const float* __restrict__ wo_b,
               float* __restrict__ out)
{
    extern __shared__ __align__(16) char smem[];
    const int tid  = threadIdx.x;
    const int lane = tid & 63;
    const int wid  = tid >> 6;
    const int g    = lane >> 4;
    const int l16  = lane & 15;
    const int i    = blockIdx.x;

    // ---------------- Phase 0: LayerNorm -> xn bf16 (LDS), mask bias ----------------
    {
        const int t  = tid >> 1;
        const int ch = (tid & 1) * 64;
        const float* xr = x + ((size_t)i * NJ + t) * NC + ch;
        f32x4 vx[16];
        float s0 = 0.f;
        #pragma unroll
        for (int u = 0; u < 16; ++u) {
            vx[u] = *(const f32x4*)(xr + 4 * u);
            s0 += vx[u][0] + vx[u][1] + vx[u][2] + vx[u][3];
        }
        s0 += __shfl_xor(s0, 1);
        const float mu = s0 * (1.0f / 128.0f);
        float v0 = 0.f;
        #pragma unroll
        for (int u = 0; u < 16; ++u) {
            #pragma unroll
            for (int e = 0; e < 4; ++e) { float d = vx[u][e] - mu; v0 += d * d; }
        }
        v0 += __shfl_xor(v0, 1);
        const float rs = rsqrtf(v0 * (1.0f / 128.0f) + 1e-5f);
        short* xnrow = (short*)(smem + XN_OFF + (size_t)t * XN_STR) + ch;
        #pragma unroll
        for (int u = 0; u < 16; u += 2) {
            f32x4 ga = *(const f32x4*)(ln_g + ch + 4 * u);
            f32x4 gb = *(const f32x4*)(ln_g + ch + 4 * u + 4);
            f32x4 ba = *(const f32x4*)(ln_b + ch + 4 * u);
            f32x4 bb = *(const f32x4*)(ln_b + ch + 4 * u + 4);
            bf16x8 o8;
            #pragma unroll
            for (int e = 0; e < 4; ++e) {
                o8[e]     = f2bf((vx[u][e]     - mu) * rs * ga[e] + ba[e]);
                o8[4 + e] = f2bf((vx[u + 1][e] - mu) * rs * gb[e] + bb[e]);
            }
            *(bf16x8*)(xnrow + 4 * u) = o8;
        }
        if (tid < 256) {
            ((float*)(smem + MB_OFF))[tid] = 1.0e9f * (mask[(size_t)i * NJ + tid] - 1.0f);
        }
    }
    __syncthreads();

    // ---------------- tb[h][t] = xn[t] . wb[h] (fp32, cancels in softmax) ----------------
    for (int job = tid; job < NH * NJ; job += 512) {
        const int t = job & 255;
        const int h = job >> 8;
        const short* xnrow = (const short*)(smem + XN_OFF + (size_t)t * XN_STR);
        const float* wr = wb + h * NC;
        float acc = 0.f;
        #pragma unroll
        for (int c = 0; c < NC; c += 8) {
            bf16x8 xv = *(const bf16x8*)(xnrow + c);
            f32x4 wa = *(const f32x4*)(wr + c);
            f32x4 wz = *(const f32x4*)(wr + c + 4);
            acc += bf2f(xv[0]) * wa[0] + bf2f(xv[1]) * wa[1] + bf2f(xv[2]) * wa[2] + bf2f(xv[3]) * wa[3]
                 + bf2f(xv[4]) * wz[0] + bf2f(xv[5]) * wz[1] + bf2f(xv[6]) * wz[2] + bf2f(xv[7]) * wz[3];
        }
        ((float*)(smem + TB_OFF))[h * NJ + t] = acc;
    }

    f32x4 facc[2][8];
    #pragma unroll
    for (int qt = 0; qt < 2; ++qt)
        #pragma unroll
        for (int ct = 0; ct < 8; ++ct)
            facc[qt][ct] = (f32x4){0.f, 0.f, 0.f, 0.f};

    const float SCALE = 0.17677669529663687f;  // 1/sqrt(32)
    const f32x4 z4 = {0.f, 0.f, 0.f, 0.f};

    for (int h = 0; h < NH; ++h) {
        __syncthreads();
        // ---------------- Phase A: project q,k,v for head h into LDS ----------------
        for (int chunk = wid; chunk < 12; chunk += 8) {
            const int pn = chunk >> 1;
            const int mhalf = chunk & 1;
            const int p = pn >> 1;        // 0=q 1=k 2=v
            const int nt2 = pn & 1;
            const float* w = (p == 0) ? wq : ((p == 1) ? wk : wv);
            const int drow = h * ND + nt2 * 16 + l16;
            const float* wrow = w + (size_t)drow * NC + g * 8;
            bf16x8 bfr[4];
            #pragma unroll
            for (int ks = 0; ks < 4; ++ks) {
                f32x4 a = *(const f32x4*)(wrow + ks * 32);
                f32x4 b = *(const f32x4*)(wrow + ks * 32 + 4);
                bf16x8 t8;
                #pragma unroll
                for (int e = 0; e < 4; ++e) { t8[e] = f2bf(a[e]); t8[4 + e] = f2bf(b[e]); }
                bfr[ks] = t8;
            }
            for (int mt = 0; mt < 8; ++mt) {
                const int trow = mhalf * 128 + mt * 16;
                const short* xnr = (const short*)(smem + XN_OFF + (size_t)(trow + l16) * XN_STR) + g * 8;
                f32x4 acc = z4;
                #pragma unroll
                for (int ks = 0; ks < 4; ++ks) {
                    bf16x8 av = *(const bf16x8*)(xnr + ks * 32);
                    acc = __builtin_amdgcn_mfma_f32_16x16x32_bf16(av, bfr[ks], acc, 0, 0, 0);
                }
                const int tt = trow + g * 4;
                const int dd = nt2 * 16 + l16;
                if (p < 2) {
                    char* buf = smem + (p == 0 ? Q_OFF : K_OFF);
                    #pragma unroll
                    for (int r = 0; r < 4; ++r)
                        *((short*)(buf + (size_t)(tt + r) * QK_STR) + dd) = f2bf(acc[r]);
                } else {
                    bf16x4 pk;
                    #pragma unroll
                    for (int r = 0; r < 4; ++r) pk[r] = f2bf(acc[r]);
                    *(bf16x4*)((short*)(smem + VT_OFF + (size_t)dd * VT_STR) + tt) = pk;
                }
            }
        }
        __syncthreads();

        // ---------------- Phase B: attention + fused out-projection ----------------
        char* pb = smem + PB_OFF + (size_t)wid * 16 * PB_STR;
        #pragma unroll
        for (int qt = 0; qt < 2; ++qt) {
            const int tq = wid * 32 + qt * 16;
            f32x4 tb4 = *(const f32x4*)((const float*)(smem + TB_OFF) + h * NJ + tq + g * 4);
            f32x4 mb4 = *(const f32x4*)((const float*)(smem + MB_OFF) + tq + g * 4);
            f32x4 tbmb;
            #pragma unroll
            for (int e = 0; e < 4; ++e) tbmb[e] = tb4[e] + mb4[e];

            bf16x8 qf = *(const bf16x8*)((const short*)(smem + Q_OFF + (size_t)(tq + l16) * QK_STR) + g * 8);
            f32x4 s[16];
            #pragma unroll
            for (int kt = 0; kt < 16; ++kt) {
                bf16x8 kf = *(const bf16x8*)((const short*)(smem + K_OFF + (size_t)(kt * 16 + l16) * QK_STR) + g * 8);
                s[kt] = __builtin_amdgcn_mfma_f32_16x16x32_bf16(qf, kf, z4, 0, 0, 0);
            }
            #pragma unroll
            for (int kt = 0; kt < 16; ++kt)
                #pragma unroll
                for (int r = 0; r < 4; ++r)
                    s[kt][r] = fmaf(s[kt][r], SCALE, tbmb[r]);   // fp32: masked rows collapse to -1e9 exactly

            f32x4 mx = s[0];
            #pragma unroll
            for (int kt = 1; kt < 16; ++kt)
                #pragma unroll
                for (int r = 0; r < 4; ++r) mx[r] = fmaxf(mx[r], s[kt][r]);
            #pragma unroll
            for (int d = 1; d < 16; d <<= 1)
                #pragma unroll
                for (int r = 0; r < 4; ++r) mx[r] = fmaxf(mx[r], __shfl_xor(mx[r], d));

            f32x4 sum = z4;
            #pragma unroll
            for (int kt = 0; kt < 16; ++kt)
                #pragma unroll
                for (int r = 0; r < 4; ++r) { s[kt][r] = __expf(s[kt][r] - mx[r]); sum[r] += s[kt][r]; }
            #pragma unroll
            for (int d = 1; d < 16; d <<= 1)
                #pragma unroll
                for (int r = 0; r < 4; ++r) sum[r] += __shfl_xor(sum[r], d);
            f32x4 inv;
            #pragma unroll
            for (int r = 0; r < 4; ++r) inv[r] = 1.0f / sum[r];
            #pragma unroll
            for (int kt = 0; kt < 16; ++kt)
                #pragma unroll
                for (int r = 0; r < 4; ++r) s[kt][r] *= inv[r];

            // PV in 32-key chunks via per-wave LDS round-trip (bf16)
            f32x4 oacc0 = z4, oacc1 = z4;
            #pragma unroll
            for (int c = 0; c < 8; ++c) {
                #pragma unroll
                for (int kk = 0; kk < 2; ++kk) {
                    const int kt = c * 2 + kk;
                    #pragma unroll
                    for (int r = 0; r < 4; ++r)
                        *((short*)(pb + (size_t)(g * 4 + r) * PB_STR) + kk * 16 + l16) = f2bf(s[kt][r]);
                }
                bf16x8 a   = *(const bf16x8*)((const short*)(pb + (size_t)l16 * PB_STR) + g * 8);
                bf16x8 vb0 = *(const bf16x8*)((const short*)(smem + VT_OFF + (size_t)l16 * VT_STR) + c * 32 + g * 8);
                bf16x8 vb1 = *(const bf16x8*)((const short*)(smem + VT_OFF + (size_t)(16 + l16) * VT_STR) + c * 32 + g * 8);
                oacc0 = __builtin_amdgcn_mfma_f32_16x16x32_bf16(a, vb0, oacc0, 0, 0, 0);
                oacc1 = __builtin_amdgcn_mfma_f32_16x16x32_bf16(a, vb1, oacc1, 0, 0, 0);
            }

            // fused out-projection: facc += o_h @ wo[:, h*32:(h+1)*32]^T
            #pragma unroll
            for (int r = 0; r < 4; ++r) {
                *((short*)(pb + (size_t)(g * 4 + r) * PB_STR) + l16)      = f2bf(oacc0[r]);
                *((short*)(pb + (size_t)(g * 4 + r) * PB_STR) + 16 + l16) = f2bf(oacc1[r]);
            }
            bf16x8 oa = *(const bf16x8*)((const short*)(pb + (size_t)l16 * PB_STR) + g * 8);
            #pragma unroll
            for (int ct = 0; ct < 8; ++ct) {
                const float* wrow = wo + (size_t)(ct * 16 + l16) * NC + h * ND + g * 8;
                f32x4 a4 = *(const f32x4*)(wrow);
                f32x4 b4 = *(const f32x4*)(wrow + 4);
                bf16x8 wf;
                #pragma unroll
                for (int e = 0; e < 4; ++e) { wf[e] = f2bf(a4[e]); wf[4 + e] = f2bf(b4[e]); }
                facc[qt][ct] = __builtin_amdgcn_mfma_f32_16x16x32_bf16(oa, wf, facc[qt][ct], 0, 0, 0);
            }
        }
    }

    // ---------------- store out = facc + wo_b ----------------
    #pragma unroll
    for (int ct = 0; ct < 8; ++ct) {
        const int col = ct * 16 + l16;
        const float bias = wo_b[col];
        #pragma unroll
        for (int qt = 0; qt < 2; ++qt) {
            const int trow = wid * 32 + qt * 16 + g * 4;
            #pragma unroll
            for (int r = 0; r < 4; ++r)
                out[((size_t)i * NJ + trow + r) * NC + col] = facc[qt][ct][r] + bias;
        }
    }
}

extern "C" void kernel_launch(void* const* d_in, const int* in_sizes, int n_in,
                              void* d_out, int out_size, void* d_ws, size_t ws_size,
                              hipStream_t stream) {
    const float* x    = (const float*)d_in[0];
    const float* mask = (const float*)d_in[1];
    const float* ln_g = (const float*)d_in[2];
    const float* ln_b = (const float*)d_in[3];
    const float* wq   = (const float*)d_in[4];
    const float* wk   = (const float*)d_in[5];
    const float* wv   = (const float*)d_in[6];
    const float* wb   = (const float*)d_in[7];
    const float* wo   = (const float*)d_in[8];
    const float* wo_b = (const float*)d_in[9];
    float* out = (float*)d_out;

    // >64KB dynamic LDS: set the attribute (idempotent, host-side; safe under capture)
    (void)hipFuncSetAttribute((const void*)fta_fused,
                              hipFuncAttributeMaxDynamicSharedMemorySize, SMEM_BYTES);

    fta_fused<<<dim3(NI), dim3(512), SMEM_BYTES, stream>>>(
        x, mask, ln_g, ln_b, wq, wk, wv, wb, wo, wo_b, out);
}